// Round 9
// baseline (8026.370 us; speedup 1.0000x reference)
//
#include <hip/hip_runtime.h>
#include <hip/hip_bf16.h>

#define VOCAB 30522
#define EMB   768
#define HID   1024
#define SEQ   4096
#define NG    4096   // 4*HID gate rows
#define NWG   128    // workgroups in persistent recurrence kernel
#define RT    256    // threads per recurrence workgroup (4 waves)
#define NMIR  8      // slot-array mirrors (poll-traffic spreading)

static __device__ __forceinline__ unsigned short f32_to_bf16(float f) {
  unsigned u = __float_as_uint(f);
  u = (u + 0x7fffu + ((u >> 16) & 1u)) >> 16;   // round-to-nearest-even
  return (unsigned short)u;
}

// ---------------------------------------------------------------------------
// Kernel 1: xg[t][r] = dot(emb[sentence[t]], w_ih[r]) + b_ih[r] + b_hh[r]
// f32 tiled GEMM, output bf16. M=SEQ, N=NG, K=EMB.
// ---------------------------------------------------------------------------
#define BM 64
#define BN 64
#define BK 16

__global__ __launch_bounds__(256) void xg_gemm(
    const int* __restrict__ sent, const float* __restrict__ emb,
    const float* __restrict__ w_ih, const float* __restrict__ b_ih,
    const float* __restrict__ b_hh, __hip_bfloat16* __restrict__ xg) {
  __shared__ float As[BK][BM + 4];
  __shared__ float Bs[BK][BN + 4];
  const int tid = threadIdx.x;
  const int n0 = blockIdx.x * BN;
  const int m0 = blockIdx.y * BM;
  const int tx = tid & 15, ty = tid >> 4;       // 16 x 16 thread grid, 4x4 per thread
  const int lr = tid >> 2;                      // 0..63 tile row for loading
  const int lk = (tid & 3) * 4;                 // 0,4,8,12 k-offset for loading

  const int arow = sent[m0 + lr];
  const float* aptr = emb + (size_t)arow * EMB + lk;
  const float* bptr = w_ih + (size_t)(n0 + lr) * EMB + lk;

  float acc[4][4] = {};

  for (int k0 = 0; k0 < EMB; k0 += BK) {
    float4 av = *(const float4*)(aptr + k0);
    float4 bv = *(const float4*)(bptr + k0);
    __syncthreads();
    As[lk + 0][lr] = av.x; As[lk + 1][lr] = av.y;
    As[lk + 2][lr] = av.z; As[lk + 3][lr] = av.w;
    Bs[lk + 0][lr] = bv.x; Bs[lk + 1][lr] = bv.y;
    Bs[lk + 2][lr] = bv.z; Bs[lk + 3][lr] = bv.w;
    __syncthreads();
#pragma unroll
    for (int k = 0; k < BK; ++k) {
      float4 a = *(const float4*)&As[k][ty * 4];
      float4 b = *(const float4*)&Bs[k][tx * 4];
      acc[0][0] = fmaf(a.x, b.x, acc[0][0]); acc[0][1] = fmaf(a.x, b.y, acc[0][1]);
      acc[0][2] = fmaf(a.x, b.z, acc[0][2]); acc[0][3] = fmaf(a.x, b.w, acc[0][3]);
      acc[1][0] = fmaf(a.y, b.x, acc[1][0]); acc[1][1] = fmaf(a.y, b.y, acc[1][1]);
      acc[1][2] = fmaf(a.y, b.z, acc[1][2]); acc[1][3] = fmaf(a.y, b.w, acc[1][3]);
      acc[2][0] = fmaf(a.z, b.x, acc[2][0]); acc[2][1] = fmaf(a.z, b.y, acc[2][1]);
      acc[2][2] = fmaf(a.z, b.z, acc[2][2]); acc[2][3] = fmaf(a.z, b.w, acc[2][3]);
      acc[3][0] = fmaf(a.w, b.x, acc[3][0]); acc[3][1] = fmaf(a.w, b.y, acc[3][1]);
      acc[3][2] = fmaf(a.w, b.z, acc[3][2]); acc[3][3] = fmaf(a.w, b.w, acc[3][3]);
    }
  }

#pragma unroll
  for (int i = 0; i < 4; ++i) {
    int gm = m0 + ty * 4 + i;
#pragma unroll
    for (int j = 0; j < 4; ++j) {
      int gn = n0 + tx * 4 + j;
      float v = acc[i][j] + b_ih[gn] + b_hh[gn];
      xg[(size_t)gm * NG + gn] = __float2bfloat16(v);
    }
  }
}

// ---------------------------------------------------------------------------
// Kernel 2: persistent LSTM recurrence, MIRRORED SLOTS (poll-rate spreading).
// 128 WGs x 256 threads. Wave wv owns h pair (h = wg*8 + 2wv, +1) and its
// 8 gate rows s = 2q+m. Weights: 64 packed-bf16 u32 VGPRs/lane, asm-pinned
// (proven register-resident, VGPR=92 in rounds 5/6).
// Sync: one 8B word per producing wave (tag32<<32 | bf16(h1)<<16 | bf16(h0)),
// relaxed agent atomics, double-buffered 512-word arrays, REPLICATED IN 8
// MIRRORS. Producers store to all 8 mirrors (off critical path); consumer
// WG g polls ONLY mirror g>>4 -> 16 WGs per mirror -> per-cache-line poll
// request rate cut 8x (rounds 5-8 all had the full machine hammering one
// copy; this is the untested variable behind three neutral results).
// Wave 0 polls (lane L owns words {64k+L}), stages to LDS; barrier.
// Race-free: tag t+1 on ANY mirror for wave w implies w's WG fully staged
// tag t; all-512 t+1 tags on my mirror implies every WG consumed t, so no
// t+2 store (to any mirror) can race my staging of t+1.
// ---------------------------------------------------------------------------
__global__ __launch_bounds__(RT, 1) void lstm_rec(
    const float* __restrict__ w_hh, const __hip_bfloat16* __restrict__ xg,
    unsigned long long* __restrict__ slots) {
  __shared__ unsigned hl[2][512];   // staged packed-bf16 h pairs (4 KB)

  const int tid  = threadIdx.x;
  const int wg   = blockIdx.x;
  const int lane = tid & 63;
  const int wv   = tid >> 6;     // wave 0..3
  const int c    = lane;         // column-pair chunk 0..63
  const int m    = lane & 1;     // which h of the pair this lane tracks
  const int mid  = wg >> 4;      // my mirror (16 WGs per mirror)

  // --- one-time: load + pack this lane's 128 w_hh weights into 64 u32 ---
  unsigned wp[8][8];
#pragma unroll
  for (int s = 0; s < 8; ++s) {
    const int q = s >> 1, mm = s & 1;
    const int gr = q * HID + wg * 8 + 2 * wv + mm;
    const float* wr = w_hh + (size_t)gr * HID;
#pragma unroll
    for (int k = 0; k < 8; ++k) {
      float2 wv2 = *(const float2*)(wr + 2 * (c + 64 * k));
      wp[s][k] = ((unsigned)f32_to_bf16(wv2.y) << 16) | (unsigned)f32_to_bf16(wv2.x);
    }
  }
#pragma unroll
  for (int s = 0; s < 8; ++s)
#pragma unroll
    for (int k = 0; k < 8; ++k)
      asm volatile("" : "+v"(wp[s][k]));

  float cst = 0.f;               // cell state (valid on lanes 0,1; uniform code)

  for (int t = 0; t < SEQ; ++t) {
    // per-lane xg prefetch: lane L (<8) loads gate (L>>1), h-offset (L&1)
    float xqv = 0.f;
    if (lane < 8) {
      const int q = lane >> 1;
      xqv = __bfloat162float(
          xg[(size_t)t * NG + q * HID + wg * 8 + 2 * wv + (lane & 1)]);
    }

    // single-wave poll of MY mirror + stage
    if (wv == 0) {
      const unsigned long long want = (unsigned long long)t;
      unsigned long long* sb = slots + (mid << 10) + ((t & 1) << 9);
      unsigned long long v[8];
      for (;;) {
#pragma unroll
        for (int k = 0; k < 8; ++k)
          v[k] = __hip_atomic_load(sb + 64 * k + lane,
                                   __ATOMIC_RELAXED, __HIP_MEMORY_SCOPE_AGENT);
        bool ok = true;
#pragma unroll
        for (int k = 0; k < 8; ++k) ok &= ((v[k] >> 32) == want);
        if (ok) break;
      }
#pragma unroll
      for (int k = 0; k < 8; ++k)
        hl[t & 1][64 * k + lane] = (unsigned)v[k];
    }
    __syncthreads();

    // unpack my h chunk once (8 words -> 16 f32), reuse for all 8 rows
    const unsigned* hb = hl[t & 1];
    float hx[8], hy[8];
#pragma unroll
    for (int k = 0; k < 8; ++k) {
      unsigned hw = hb[c + 64 * k];
      hx[k] = __uint_as_float(hw << 16);
      hy[k] = __uint_as_float(hw & 0xffff0000u);
    }

    float acc[8];
#pragma unroll
    for (int s = 0; s < 8; ++s) {
      float a = 0.f;
#pragma unroll
      for (int k = 0; k < 8; ++k) {
        unsigned w = wp[s][k];
        a = fmaf(__uint_as_float(w << 16),         hx[k], a);
        a = fmaf(__uint_as_float(w & 0xffff0000u), hy[k], a);
      }
      acc[s] = a;
    }

    // folding tree: 8 partial sums x 64 lanes -> lane L holds S_{L&7}
#pragma unroll
    for (int M = 1, n = 8; M <= 4; M <<= 1, n >>= 1) {
#pragma unroll
      for (int j = 0; j < 4; ++j) {
        if (j < (n >> 1)) {
          float u  = (lane & M) ? acc[2 * j + 1] : acc[2 * j];
          float u2 = (lane & M) ? acc[2 * j]     : acc[2 * j + 1];
          acc[j] = u + __shfl_xor(u2, M, 64);
        }
      }
    }
    float r = acc[0];
    r += __shfl_xor(r, 8, 64);
    r += __shfl_xor(r, 16, 64);
    r += __shfl_xor(r, 32, 64);
    // r at lane L == full gate sum for s = L&7

    // per-lane nonlinearity (parallel): s=4,5 -> tanh via scaled sigmoid
    {
      const int s = lane & 7;
      const bool isg = (s >> 1) == 2;
      float z = r + xqv;
      z = isg ? 2.f * z : z;
      float sg = 1.f / (1.f + __expf(-z));
      r = isg ? fmaf(2.f, sg, -1.f) : sg;   // activated gate value
    }

    // gather activated gates for my h (m = lane&1): i=s(m), f=s(2+m), g=s(4+m), o=s(6+m)
    float i_ = __shfl(r, m,     64);
    float f_ = __shfl(r, 2 + m, 64);
    float g_ = __shfl(r, 4 + m, 64);
    float o_ = __shfl(r, 6 + m, 64);

    cst = fmaf(f_, cst, i_ * g_);
    // tanh(c) via scaled sigmoid: 2*sig(2c) - 1
    float th = fmaf(2.f, 1.f / (1.f + __expf(-2.f * cst)), -1.f);
    float hn = o_ * th;

    float hn1 = __shfl(hn, 1, 64);
    if (lane == 0) {
      unsigned payload = ((unsigned)f32_to_bf16(hn1) << 16) | (unsigned)f32_to_bf16(hn);
      unsigned long long pv =
          ((unsigned long long)(unsigned)(t + 1) << 32) | (unsigned long long)payload;
      unsigned long long* dst =
          slots + (((t + 1) & 1) << 9) + (wg * 4 + wv);
#pragma unroll
      for (int mm = 0; mm < NMIR; ++mm)
        __hip_atomic_store(dst + (mm << 10), pv,
                           __ATOMIC_RELAXED, __HIP_MEMORY_SCOPE_AGENT);
    }
    // no trailing barrier: next staging targets the other LDS buffer, and
    // tag t+2 cannot appear before every WG fully consumed tag t.
  }
}

// ---------------------------------------------------------------------------
// Kernel 3: y = h_T @ w_out.T + b_out ; log_softmax. h_T = mirror-0 buf0.
// ---------------------------------------------------------------------------
__global__ __launch_bounds__(256) void head_kernel(
    const unsigned long long* __restrict__ hslots, const float* __restrict__ w_out,
    const float* __restrict__ b_out, float* __restrict__ out) {
  __shared__ float s0[256], s1[256];
  const int tid = threadIdx.x;
  float p0 = 0.f, p1 = 0.f;
  for (int w = tid; w < 512; w += 256) {
    unsigned pw = (unsigned)hslots[w];
    float h0 = __uint_as_float(pw << 16);
    float h1 = __uint_as_float(pw & 0xffff0000u);
    p0 = fmaf(h0, w_out[2 * w], fmaf(h1, w_out[2 * w + 1], p0));
    p1 = fmaf(h0, w_out[HID + 2 * w], fmaf(h1, w_out[HID + 2 * w + 1], p1));
  }
  s0[tid] = p0; s1[tid] = p1;
  __syncthreads();
  for (int off = 128; off; off >>= 1) {
    if (tid < off) { s0[tid] += s0[tid + off]; s1[tid] += s1[tid + off]; }
    __syncthreads();
  }
  if (tid == 0) {
    float y0 = s0[0] + b_out[0], y1 = s1[0] + b_out[1];
    float mx = fmaxf(y0, y1);
    float lse = mx + logf(expf(y0 - mx) + expf(y1 - mx));
    out[0] = y0 - lse;
    out[1] = y1 - lse;
  }
}

// ---------------------------------------------------------------------------
extern "C" void kernel_launch(void* const* d_in, const int* in_sizes, int n_in,
                              void* d_out, int out_size, void* d_ws, size_t ws_size,
                              hipStream_t stream) {
  const int*   sent  = (const int*)d_in[0];
  const float* emb   = (const float*)d_in[1];
  const float* w_ih  = (const float*)d_in[2];
  const float* w_hh  = (const float*)d_in[3];
  const float* b_ih  = (const float*)d_in[4];
  const float* b_hh  = (const float*)d_in[5];
  const float* w_out = (const float*)d_in[6];
  const float* b_out = (const float*)d_in[7];
  float* out = (float*)d_out;

  // workspace layout: 8 mirrors x 2 buffers x 512 x 8B = 64 KB, then xg
  unsigned long long* slots = (unsigned long long*)d_ws;
  __hip_bfloat16* xg = (__hip_bfloat16*)((char*)d_ws + 65536);   // SEQ*NG bf16

  // zero all mirror slot tags (= h_0 state at epoch 0) every launch/replay
  hipMemsetAsync(d_ws, 0, 65536, stream);

  // xg GEMM
  dim3 ggrid(NG / BN, SEQ / BM);
  xg_gemm<<<ggrid, 256, 0, stream>>>(sent, emb, w_ih, b_ih, b_hh, xg);

  // persistent recurrence (128 WGs << 256 CUs -> always co-resident)
  lstm_rec<<<NWG, RT, 0, stream>>>(w_hh, xg, slots);

  // head: final h tagged 4096 lives in mirror 0, buffer 0
  head_kernel<<<1, 256, 0, stream>>>(slots, w_out, b_out, out);
}

// Round 10
// 7499.172 us; speedup vs baseline: 1.0703x; 1.0703x over previous
//
#include <hip/hip_runtime.h>
#include <hip/hip_bf16.h>

#define VOCAB 30522
#define EMB   768
#define HID   1024
#define SEQ   4096
#define NG    4096   // 4*HID gate rows
#define NWG   128    // workgroups in persistent recurrence kernel
#define RT    256    // threads per recurrence workgroup (4 waves)

static __device__ __forceinline__ unsigned short f32_to_bf16(float f) {
  unsigned u = __float_as_uint(f);
  u = (u + 0x7fffu + ((u >> 16) & 1u)) >> 16;   // round-to-nearest-even
  return (unsigned short)u;
}

// ---------------------------------------------------------------------------
// Kernel 1: xg[t][r] = dot(emb[sentence[t]], w_ih[r]) + b_ih[r] + b_hh[r]
// f32 tiled GEMM. OVERLAPPED with lstm_rec: xg written via device-scope
// relaxed atomic 8B stores (write-through to the coherence point), then
// __syncthreads (per-thread vmcnt drain) + one flag atomicAdd per block.
// Grid: blockIdx.x = col tile (fast), blockIdx.y = row block -> row blocks
// are dispatched in consumption order.
// ---------------------------------------------------------------------------
#define BM 64
#define BN 64
#define BK 16

__global__ __launch_bounds__(256) void xg_gemm(
    const int* __restrict__ sent, const float* __restrict__ emb,
    const float* __restrict__ w_ih, const float* __restrict__ b_ih,
    const float* __restrict__ b_hh, unsigned long long* __restrict__ xg64,
    int* __restrict__ flags) {
  __shared__ float As[BK][BM + 4];
  __shared__ float Bs[BK][BN + 4];
  const int tid = threadIdx.x;
  const int n0 = blockIdx.x * BN;
  const int m0 = blockIdx.y * BM;
  const int tx = tid & 15, ty = tid >> 4;       // 16 x 16 thread grid, 4x4 per thread
  const int lr = tid >> 2;                      // 0..63 tile row for loading
  const int lk = (tid & 3) * 4;                 // 0,4,8,12 k-offset for loading

  const int arow = sent[m0 + lr];
  const float* aptr = emb + (size_t)arow * EMB + lk;
  const float* bptr = w_ih + (size_t)(n0 + lr) * EMB + lk;

  float acc[4][4] = {};

  for (int k0 = 0; k0 < EMB; k0 += BK) {
    float4 av = *(const float4*)(aptr + k0);
    float4 bv = *(const float4*)(bptr + k0);
    __syncthreads();
    As[lk + 0][lr] = av.x; As[lk + 1][lr] = av.y;
    As[lk + 2][lr] = av.z; As[lk + 3][lr] = av.w;
    Bs[lk + 0][lr] = bv.x; Bs[lk + 1][lr] = bv.y;
    Bs[lk + 2][lr] = bv.z; Bs[lk + 3][lr] = bv.w;
    __syncthreads();
#pragma unroll
    for (int k = 0; k < BK; ++k) {
      float4 a = *(const float4*)&As[k][ty * 4];
      float4 b = *(const float4*)&Bs[k][tx * 4];
      acc[0][0] = fmaf(a.x, b.x, acc[0][0]); acc[0][1] = fmaf(a.x, b.y, acc[0][1]);
      acc[0][2] = fmaf(a.x, b.z, acc[0][2]); acc[0][3] = fmaf(a.x, b.w, acc[0][3]);
      acc[1][0] = fmaf(a.y, b.x, acc[1][0]); acc[1][1] = fmaf(a.y, b.y, acc[1][1]);
      acc[1][2] = fmaf(a.y, b.z, acc[1][2]); acc[1][3] = fmaf(a.y, b.w, acc[1][3]);
      acc[2][0] = fmaf(a.z, b.x, acc[2][0]); acc[2][1] = fmaf(a.z, b.y, acc[2][1]);
      acc[2][2] = fmaf(a.z, b.z, acc[2][2]); acc[2][3] = fmaf(a.z, b.w, acc[2][3]);
      acc[3][0] = fmaf(a.w, b.x, acc[3][0]); acc[3][1] = fmaf(a.w, b.y, acc[3][1]);
      acc[3][2] = fmaf(a.w, b.z, acc[3][2]); acc[3][3] = fmaf(a.w, b.w, acc[3][3]);
    }
  }

  const int gbase = n0 + tx * 4;
  const float b0 = b_ih[gbase]     + b_hh[gbase];
  const float b1 = b_ih[gbase + 1] + b_hh[gbase + 1];
  const float b2 = b_ih[gbase + 2] + b_hh[gbase + 2];
  const float b3 = b_ih[gbase + 3] + b_hh[gbase + 3];
#pragma unroll
  for (int i = 0; i < 4; ++i) {
    const int gm = m0 + ty * 4 + i;
    unsigned lo = ((unsigned)f32_to_bf16(acc[i][1] + b1) << 16) |
                  (unsigned)f32_to_bf16(acc[i][0] + b0);
    unsigned hi = ((unsigned)f32_to_bf16(acc[i][3] + b3) << 16) |
                  (unsigned)f32_to_bf16(acc[i][2] + b2);
    unsigned long long wrd = ((unsigned long long)hi << 32) | lo;
    __hip_atomic_store(xg64 + (size_t)gm * (NG / 4) + (gbase >> 2), wrd,
                       __ATOMIC_RELAXED, __HIP_MEMORY_SCOPE_AGENT);
  }
  __syncthreads();   // vmcnt(0) drain per thread: all stores at coherence point
  if (tid == 0)
    __hip_atomic_fetch_add(flags + blockIdx.y, 1,
                           __ATOMIC_RELAXED, __HIP_MEMORY_SCOPE_AGENT);
}

// ---------------------------------------------------------------------------
// Kernel 2: persistent LSTM recurrence (round-8 sync, no mirrors) overlapped
// with xg_gemm. 128 WGs x 256 threads; wave wv owns h pair (wg*8+2wv, +1),
// 8 gate rows s=2q+m. Weights: 64 packed-bf16 u32 VGPRs/lane, asm-pinned
// (proven register-resident). Slots: one 8B word per producing wave
// (tag32<<32 | bf16(h1)<<16 | bf16(h0)), relaxed agent atomics, double-
// buffered 512-word arrays; SELF-INITIALIZED (each wave publishes tag 0 /
// h=0 for its own word -> no slot memset; consumers spin until it lands).
// Wave 0 polls (lane L owns words {64k+L}), stages to LDS; barrier.
// xg gating: row-block b ready when flags[b]==64; wave 0 checks the NEXT
// block's flag one step early (t+1 multiple of 64), ordered before all
// waves' step-(t+1) xg loads by the step-t barrier. xg read via device-
// scope relaxed atomic u32 loads (no stale-cache path during overlap).
// Race-freedom of slots unchanged: tag t+2 cannot appear in a buffer slot
// before every WG fully consumed tag t (staging precedes publish via the
// barrier; consuming all 512 tag-(t+1) words implies all WGs staged tag t).
// ---------------------------------------------------------------------------
__global__ __launch_bounds__(RT, 1) void lstm_rec(
    const float* __restrict__ w_hh, const unsigned* __restrict__ xg32,
    unsigned long long* __restrict__ slots, int* __restrict__ flags) {
  __shared__ unsigned hl[2][512];   // staged packed-bf16 h pairs (4 KB)

  const int tid  = threadIdx.x;
  const int wg   = blockIdx.x;
  const int lane = tid & 63;
  const int wv   = tid >> 6;     // wave 0..3
  const int c    = lane;         // column-pair chunk 0..63
  const int m    = lane & 1;     // which h of the pair this lane tracks

  // --- one-time: load + pack this lane's 128 w_hh weights into 64 u32 ---
  unsigned wp[8][8];
#pragma unroll
  for (int s = 0; s < 8; ++s) {
    const int q = s >> 1, mm = s & 1;
    const int gr = q * HID + wg * 8 + 2 * wv + mm;
    const float* wr = w_hh + (size_t)gr * HID;
#pragma unroll
    for (int k = 0; k < 8; ++k) {
      float2 wv2 = *(const float2*)(wr + 2 * (c + 64 * k));
      wp[s][k] = ((unsigned)f32_to_bf16(wv2.y) << 16) | (unsigned)f32_to_bf16(wv2.x);
    }
  }
#pragma unroll
  for (int s = 0; s < 8; ++s)
#pragma unroll
    for (int k = 0; k < 8; ++k)
      asm volatile("" : "+v"(wp[s][k]));

  // self-init my slot word: tag 0, payload h0 = (0,0)
  if (lane == 0)
    __hip_atomic_store(slots + (wg * 4 + wv), 0ULL,
                       __ATOMIC_RELAXED, __HIP_MEMORY_SCOPE_AGENT);
  // gate row-block 0 of xg before any step-0 xg load
  if (wv == 0) {
    while (__hip_atomic_load(flags, __ATOMIC_RELAXED, __HIP_MEMORY_SCOPE_AGENT) < 64) {}
  }
  __syncthreads();

  float cst = 0.f;               // cell state (valid on lanes 0,1; uniform code)

  for (int t = 0; t < SEQ; ++t) {
    // per-lane xg prefetch (device-scope atomic u32; latency hides under poll)
    float xqv = 0.f;
    if (lane < 8) {
      const int q = lane >> 1;
      unsigned w = __hip_atomic_load(
          xg32 + ((size_t)t * (NG / 2) + q * (HID / 2) + wg * 4 + wv),
          __ATOMIC_RELAXED, __HIP_MEMORY_SCOPE_AGENT);
      xqv = __uint_as_float((lane & 1) ? (w & 0xffff0000u) : (w << 16));
    }

    if (wv == 0) {
      // gate the NEXT row-block one step early (ordered by this step's barrier)
      if (((t + 1) & 63) == 0 && (t + 1) < SEQ) {
        const int nb = (t + 1) >> 6;
        while (__hip_atomic_load(flags + nb, __ATOMIC_RELAXED,
                                 __HIP_MEMORY_SCOPE_AGENT) < 64) {}
      }
      // single-wave poll + stage: lane owns words {64k + lane}
      const unsigned long long want = (unsigned long long)t;
      unsigned long long* sb = slots + ((t & 1) << 9);
      unsigned long long v[8];
      for (;;) {
#pragma unroll
        for (int k = 0; k < 8; ++k)
          v[k] = __hip_atomic_load(sb + 64 * k + lane,
                                   __ATOMIC_RELAXED, __HIP_MEMORY_SCOPE_AGENT);
        bool ok = true;
#pragma unroll
        for (int k = 0; k < 8; ++k) ok &= ((v[k] >> 32) == want);
        if (ok) break;
      }
#pragma unroll
      for (int k = 0; k < 8; ++k)
        hl[t & 1][64 * k + lane] = (unsigned)v[k];
    }
    __syncthreads();

    // unpack my h chunk once (8 words -> 16 f32), reuse for all 8 rows
    const unsigned* hb = hl[t & 1];
    float hx[8], hy[8];
#pragma unroll
    for (int k = 0; k < 8; ++k) {
      unsigned hw = hb[c + 64 * k];
      hx[k] = __uint_as_float(hw << 16);
      hy[k] = __uint_as_float(hw & 0xffff0000u);
    }

    float acc[8];
#pragma unroll
    for (int s = 0; s < 8; ++s) {
      float a = 0.f;
#pragma unroll
      for (int k = 0; k < 8; ++k) {
        unsigned w = wp[s][k];
        a = fmaf(__uint_as_float(w << 16),         hx[k], a);
        a = fmaf(__uint_as_float(w & 0xffff0000u), hy[k], a);
      }
      acc[s] = a;
    }

    // folding tree: 8 partial sums x 64 lanes -> lane L holds S_{L&7}
#pragma unroll
    for (int M = 1, n = 8; M <= 4; M <<= 1, n >>= 1) {
#pragma unroll
      for (int j = 0; j < 4; ++j) {
        if (j < (n >> 1)) {
          float u  = (lane & M) ? acc[2 * j + 1] : acc[2 * j];
          float u2 = (lane & M) ? acc[2 * j]     : acc[2 * j + 1];
          acc[j] = u + __shfl_xor(u2, M, 64);
        }
      }
    }
    float r = acc[0];
    r += __shfl_xor(r, 8, 64);
    r += __shfl_xor(r, 16, 64);
    r += __shfl_xor(r, 32, 64);
    // r at lane L == full gate sum for s = L&7

    // per-lane nonlinearity (parallel): s=4,5 -> tanh via scaled sigmoid
    {
      const int s = lane & 7;
      const bool isg = (s >> 1) == 2;
      float z = r + xqv;
      z = isg ? 2.f * z : z;
      float sg = 1.f / (1.f + __expf(-z));
      r = isg ? fmaf(2.f, sg, -1.f) : sg;   // activated gate value
    }

    // gather activated gates for my h (m = lane&1)
    float i_ = __shfl(r, m,     64);
    float f_ = __shfl(r, 2 + m, 64);
    float g_ = __shfl(r, 4 + m, 64);
    float o_ = __shfl(r, 6 + m, 64);

    cst = fmaf(f_, cst, i_ * g_);
    float th = fmaf(2.f, 1.f / (1.f + __expf(-2.f * cst)), -1.f);
    float hn = o_ * th;

    float hn1 = __shfl(hn, 1, 64);
    if (lane == 0) {
      unsigned payload = ((unsigned)f32_to_bf16(hn1) << 16) | (unsigned)f32_to_bf16(hn);
      unsigned long long pv =
          ((unsigned long long)(unsigned)(t + 1) << 32) | (unsigned long long)payload;
      __hip_atomic_store(slots + (((t + 1) & 1) << 9) + (wg * 4 + wv), pv,
                         __ATOMIC_RELAXED, __HIP_MEMORY_SCOPE_AGENT);
    }
    // no trailing barrier: next staging targets the other LDS buffer, and
    // tag t+2 cannot appear before every WG fully consumed tag t.
  }
}

// ---------------------------------------------------------------------------
// Kernel 3: y = h_T @ w_out.T + b_out ; log_softmax. h_T = slots buf0 packed.
// ---------------------------------------------------------------------------
__global__ __launch_bounds__(256) void head_kernel(
    const unsigned long long* __restrict__ hslots, const float* __restrict__ w_out,
    const float* __restrict__ b_out, float* __restrict__ out) {
  __shared__ float s0[256], s1[256];
  const int tid = threadIdx.x;
  float p0 = 0.f, p1 = 0.f;
  for (int w = tid; w < 512; w += 256) {
    unsigned pw = (unsigned)hslots[w];
    float h0 = __uint_as_float(pw << 16);
    float h1 = __uint_as_float(pw & 0xffff0000u);
    p0 = fmaf(h0, w_out[2 * w], fmaf(h1, w_out[2 * w + 1], p0));
    p1 = fmaf(h0, w_out[HID + 2 * w], fmaf(h1, w_out[HID + 2 * w + 1], p1));
  }
  s0[tid] = p0; s1[tid] = p1;
  __syncthreads();
  for (int off = 128; off; off >>= 1) {
    if (tid < off) { s0[tid] += s0[tid + off]; s1[tid] += s1[tid + off]; }
    __syncthreads();
  }
  if (tid == 0) {
    float y0 = s0[0] + b_out[0], y1 = s1[0] + b_out[1];
    float mx = fmaxf(y0, y1);
    float lse = mx + logf(expf(y0 - mx) + expf(y1 - mx));
    out[0] = y0 - lse;
    out[1] = y1 - lse;
  }
}

// ---------------------------------------------------------------------------
extern "C" void kernel_launch(void* const* d_in, const int* in_sizes, int n_in,
                              void* d_out, int out_size, void* d_ws, size_t ws_size,
                              hipStream_t stream) {
  const int*   sent  = (const int*)d_in[0];
  const float* emb   = (const float*)d_in[1];
  const float* w_ih  = (const float*)d_in[2];
  const float* w_hh  = (const float*)d_in[3];
  const float* b_ih  = (const float*)d_in[4];
  const float* b_hh  = (const float*)d_in[5];
  const float* w_out = (const float*)d_in[6];
  const float* b_out = (const float*)d_in[7];
  float* out = (float*)d_out;

  // workspace layout
  unsigned long long* slots = (unsigned long long*)d_ws;       // 2*512*8 = 8 KB
  int* flags = (int*)((char*)d_ws + 8192);                     // 64 ints
  void* xg   = (char*)d_ws + 16384;                            // SEQ*NG bf16

  // only the flags need zeroing (slots self-initialize in lstm_rec)
  hipMemsetAsync(flags, 0, 256, stream);

  // xg GEMM — launched first, runs CONCURRENTLY with lstm_rec (row-block
  // ready flags gate the consumer; producer is ~10x ahead of consumption)
  dim3 ggrid(NG / BN, SEQ / BM);
  xg_gemm<<<ggrid, 256, 0, stream>>>(sent, emb, w_ih, b_ih, b_hh,
                                     (unsigned long long*)xg, flags);

  // persistent recurrence (128 WGs; co-resident alongside draining GEMM:
  // 256thr/4KB LDS/88 VGPR fits with GEMM blocks on the same CUs)
  lstm_rec<<<NWG, RT, 0, stream>>>(w_hh, (const unsigned*)xg, slots, flags);

  // head: final h tagged 4096 lives in slots buffer 0
  head_kernel<<<1, 256, 0, stream>>>(slots, w_out, b_out, out);
}

// Round 11
// 7214.692 us; speedup vs baseline: 1.1125x; 1.0394x over previous
//
#include <hip/hip_runtime.h>
#include <hip/hip_bf16.h>

#define VOCAB 30522
#define EMB   768
#define HID   1024
#define SEQ   4096
#define NG    4096   // 4*HID gate rows
#define NWG   128    // recurrence workgroups
#define NWORK 128    // GEMM worker workgroups (same kernel, blocks 128..255)
#define RT    256    // threads per workgroup (4 waves)

static __device__ __forceinline__ unsigned short f32_to_bf16(float f) {
  unsigned u = __float_as_uint(f);
  u = (u + 0x7fffu + ((u >> 16) & 1u)) >> 16;   // round-to-nearest-even
  return (unsigned short)u;
}

// ---------------------------------------------------------------------------
// Fused kernel: blocks [0,128) = persistent LSTM recurrence (round-10 body,
// unchanged sync); blocks [128,256) = persistent GEMM workers producing
// xg[t][r] = emb[sent[t]] . w_ih[r] + b_ih[r] + b_hh[r] in row-block order.
// Producer protocol (validated rounds 9-10): agent-scope relaxed atomic 8B
// stores of xg, __syncthreads (per-thread vmcnt drain), flag atomicAdd;
// consumer gates row block b on flags[b]==64 one step early and reads xg
// with agent-scope relaxed atomic loads. Same-kernel blocks co-schedule ->
// true overlap (same-stream separate kernels serialized; round-10 lesson).
// ---------------------------------------------------------------------------
#define BM 64
#define BN 64
#define BK 16

__global__ __launch_bounds__(RT, 1) void fused_lstm(
    const int* __restrict__ sent, const float* __restrict__ emb,
    const float* __restrict__ w_ih, const float* __restrict__ b_ih,
    const float* __restrict__ b_hh, const float* __restrict__ w_hh,
    unsigned long long* __restrict__ xg64, unsigned long long* __restrict__ slots,
    int* __restrict__ flags) {
  __shared__ union {
    struct { float As[BK][BM + 4]; float Bs[BK][BN + 4]; } g;   // ~8.7 KB
    unsigned hl[2][512];                                        // 4 KB
  } sm;

  const int blk = blockIdx.x;
  const int tid = threadIdx.x;

  if (blk >= NWG) {
    // ================= GEMM worker role =================
    const int widx = blk - NWG;
    const int tx = tid & 15, ty = tid >> 4;
    const int lr = tid >> 2;
    const int lk = (tid & 3) * 4;

    for (int tile = widx; tile < (SEQ / BM) * (NG / BN); tile += NWORK) {
      const int m0 = (tile >> 6) * BM;       // row block (consumption order)
      const int n0 = (tile & 63) * BN;

      const int arow = sent[m0 + lr];
      const float* aptr = emb + (size_t)arow * EMB + lk;
      const float* bptr = w_ih + (size_t)(n0 + lr) * EMB + lk;

      float acc[4][4] = {};
      for (int k0 = 0; k0 < EMB; k0 += BK) {
        float4 av = *(const float4*)(aptr + k0);
        float4 bv = *(const float4*)(bptr + k0);
        __syncthreads();
        sm.g.As[lk + 0][lr] = av.x; sm.g.As[lk + 1][lr] = av.y;
        sm.g.As[lk + 2][lr] = av.z; sm.g.As[lk + 3][lr] = av.w;
        sm.g.Bs[lk + 0][lr] = bv.x; sm.g.Bs[lk + 1][lr] = bv.y;
        sm.g.Bs[lk + 2][lr] = bv.z; sm.g.Bs[lk + 3][lr] = bv.w;
        __syncthreads();
#pragma unroll
        for (int k = 0; k < BK; ++k) {
          float4 a = *(const float4*)&sm.g.As[k][ty * 4];
          float4 b = *(const float4*)&sm.g.Bs[k][tx * 4];
          acc[0][0] = fmaf(a.x, b.x, acc[0][0]); acc[0][1] = fmaf(a.x, b.y, acc[0][1]);
          acc[0][2] = fmaf(a.x, b.z, acc[0][2]); acc[0][3] = fmaf(a.x, b.w, acc[0][3]);
          acc[1][0] = fmaf(a.y, b.x, acc[1][0]); acc[1][1] = fmaf(a.y, b.y, acc[1][1]);
          acc[1][2] = fmaf(a.y, b.z, acc[1][2]); acc[1][3] = fmaf(a.y, b.w, acc[1][3]);
          acc[2][0] = fmaf(a.z, b.x, acc[2][0]); acc[2][1] = fmaf(a.z, b.y, acc[2][1]);
          acc[2][2] = fmaf(a.z, b.z, acc[2][2]); acc[2][3] = fmaf(a.z, b.w, acc[2][3]);
          acc[3][0] = fmaf(a.w, b.x, acc[3][0]); acc[3][1] = fmaf(a.w, b.y, acc[3][1]);
          acc[3][2] = fmaf(a.w, b.z, acc[3][2]); acc[3][3] = fmaf(a.w, b.w, acc[3][3]);
        }
      }

      const int gbase = n0 + tx * 4;
      const float b0 = b_ih[gbase]     + b_hh[gbase];
      const float b1 = b_ih[gbase + 1] + b_hh[gbase + 1];
      const float b2 = b_ih[gbase + 2] + b_hh[gbase + 2];
      const float b3 = b_ih[gbase + 3] + b_hh[gbase + 3];
#pragma unroll
      for (int i = 0; i < 4; ++i) {
        const int gm = m0 + ty * 4 + i;
        unsigned lo = ((unsigned)f32_to_bf16(acc[i][1] + b1) << 16) |
                      (unsigned)f32_to_bf16(acc[i][0] + b0);
        unsigned hi = ((unsigned)f32_to_bf16(acc[i][3] + b3) << 16) |
                      (unsigned)f32_to_bf16(acc[i][2] + b2);
        unsigned long long wrd = ((unsigned long long)hi << 32) | lo;
        __hip_atomic_store(xg64 + (size_t)gm * (NG / 4) + (gbase >> 2), wrd,
                           __ATOMIC_RELAXED, __HIP_MEMORY_SCOPE_AGENT);
      }
      __syncthreads();   // per-thread vmcnt drain: stores at coherence point
      if (tid == 0)
        __hip_atomic_fetch_add(flags + (tile >> 6), 1,
                               __ATOMIC_RELAXED, __HIP_MEMORY_SCOPE_AGENT);
    }
    return;
  }

  // ================= recurrence role (round-10 body) =================
  const unsigned* xg32 = (const unsigned*)xg64;
  const int wg   = blk;
  const int lane = tid & 63;
  const int wv   = tid >> 6;     // wave 0..3
  const int c    = lane;         // column-pair chunk 0..63
  const int m    = lane & 1;     // which h of the pair this lane tracks

  // one-time: load + pack this lane's 128 w_hh weights into 64 u32
  unsigned wp[8][8];
#pragma unroll
  for (int s = 0; s < 8; ++s) {
    const int q = s >> 1, mm = s & 1;
    const int gr = q * HID + wg * 8 + 2 * wv + mm;
    const float* wr = w_hh + (size_t)gr * HID;
#pragma unroll
    for (int k = 0; k < 8; ++k) {
      float2 wv2 = *(const float2*)(wr + 2 * (c + 64 * k));
      wp[s][k] = ((unsigned)f32_to_bf16(wv2.y) << 16) | (unsigned)f32_to_bf16(wv2.x);
    }
  }
#pragma unroll
  for (int s = 0; s < 8; ++s)
#pragma unroll
    for (int k = 0; k < 8; ++k)
      asm volatile("" : "+v"(wp[s][k]));

  // self-init my slot word: tag 0, payload h0 = (0,0)
  if (lane == 0)
    __hip_atomic_store(slots + (wg * 4 + wv), 0ULL,
                       __ATOMIC_RELAXED, __HIP_MEMORY_SCOPE_AGENT);
  // gate row-block 0 of xg before any step-0 xg load
  if (wv == 0) {
    while (__hip_atomic_load(flags, __ATOMIC_RELAXED, __HIP_MEMORY_SCOPE_AGENT) < 64) {}
  }
  __syncthreads();

  float cst = 0.f;

  for (int t = 0; t < SEQ; ++t) {
    float xqv = 0.f;
    if (lane < 8) {
      const int q = lane >> 1;
      unsigned w = __hip_atomic_load(
          xg32 + ((size_t)t * (NG / 2) + q * (HID / 2) + wg * 4 + wv),
          __ATOMIC_RELAXED, __HIP_MEMORY_SCOPE_AGENT);
      xqv = __uint_as_float((lane & 1) ? (w & 0xffff0000u) : (w << 16));
    }

    if (wv == 0) {
      if (((t + 1) & 63) == 0 && (t + 1) < SEQ) {
        const int nb = (t + 1) >> 6;
        while (__hip_atomic_load(flags + nb, __ATOMIC_RELAXED,
                                 __HIP_MEMORY_SCOPE_AGENT) < 64) {}
      }
      const unsigned long long want = (unsigned long long)t;
      unsigned long long* sb = slots + ((t & 1) << 9);
      unsigned long long v[8];
      for (;;) {
#pragma unroll
        for (int k = 0; k < 8; ++k)
          v[k] = __hip_atomic_load(sb + 64 * k + lane,
                                   __ATOMIC_RELAXED, __HIP_MEMORY_SCOPE_AGENT);
        bool ok = true;
#pragma unroll
        for (int k = 0; k < 8; ++k) ok &= ((v[k] >> 32) == want);
        if (ok) break;
      }
#pragma unroll
      for (int k = 0; k < 8; ++k)
        sm.hl[t & 1][64 * k + lane] = (unsigned)v[k];
    }
    __syncthreads();

    const unsigned* hb = sm.hl[t & 1];
    float hx[8], hy[8];
#pragma unroll
    for (int k = 0; k < 8; ++k) {
      unsigned hw = hb[c + 64 * k];
      hx[k] = __uint_as_float(hw << 16);
      hy[k] = __uint_as_float(hw & 0xffff0000u);
    }

    float acc[8];
#pragma unroll
    for (int s = 0; s < 8; ++s) {
      float a = 0.f;
#pragma unroll
      for (int k = 0; k < 8; ++k) {
        unsigned w = wp[s][k];
        a = fmaf(__uint_as_float(w << 16),         hx[k], a);
        a = fmaf(__uint_as_float(w & 0xffff0000u), hy[k], a);
      }
      acc[s] = a;
    }

#pragma unroll
    for (int M = 1, n = 8; M <= 4; M <<= 1, n >>= 1) {
#pragma unroll
      for (int j = 0; j < 4; ++j) {
        if (j < (n >> 1)) {
          float u  = (lane & M) ? acc[2 * j + 1] : acc[2 * j];
          float u2 = (lane & M) ? acc[2 * j]     : acc[2 * j + 1];
          acc[j] = u + __shfl_xor(u2, M, 64);
        }
      }
    }
    float r = acc[0];
    r += __shfl_xor(r, 8, 64);
    r += __shfl_xor(r, 16, 64);
    r += __shfl_xor(r, 32, 64);

    {
      const int s = lane & 7;
      const bool isg = (s >> 1) == 2;
      float z = r + xqv;
      z = isg ? 2.f * z : z;
      float sg = 1.f / (1.f + __expf(-z));
      r = isg ? fmaf(2.f, sg, -1.f) : sg;
    }

    float i_ = __shfl(r, m,     64);
    float f_ = __shfl(r, 2 + m, 64);
    float g_ = __shfl(r, 4 + m, 64);
    float o_ = __shfl(r, 6 + m, 64);

    cst = fmaf(f_, cst, i_ * g_);
    float th = fmaf(2.f, 1.f / (1.f + __expf(-2.f * cst)), -1.f);
    float hn = o_ * th;

    float hn1 = __shfl(hn, 1, 64);
    if (lane == 0) {
      unsigned payload = ((unsigned)f32_to_bf16(hn1) << 16) | (unsigned)f32_to_bf16(hn);
      unsigned long long pv =
          ((unsigned long long)(unsigned)(t + 1) << 32) | (unsigned long long)payload;
      __hip_atomic_store(slots + (((t + 1) & 1) << 9) + (wg * 4 + wv), pv,
                         __ATOMIC_RELAXED, __HIP_MEMORY_SCOPE_AGENT);
    }
  }
}

// ---------------------------------------------------------------------------
// Head: y = h_T @ w_out.T + b_out ; log_softmax. h_T = slots buf0 packed.
// ---------------------------------------------------------------------------
__global__ __launch_bounds__(256) void head_kernel(
    const unsigned long long* __restrict__ hslots, const float* __restrict__ w_out,
    const float* __restrict__ b_out, float* __restrict__ out) {
  __shared__ float s0[256], s1[256];
  const int tid = threadIdx.x;
  float p0 = 0.f, p1 = 0.f;
  for (int w = tid; w < 512; w += 256) {
    unsigned pw = (unsigned)hslots[w];
    float h0 = __uint_as_float(pw << 16);
    float h1 = __uint_as_float(pw & 0xffff0000u);
    p0 = fmaf(h0, w_out[2 * w], fmaf(h1, w_out[2 * w + 1], p0));
    p1 = fmaf(h0, w_out[HID + 2 * w], fmaf(h1, w_out[HID + 2 * w + 1], p1));
  }
  s0[tid] = p0; s1[tid] = p1;
  __syncthreads();
  for (int off = 128; off; off >>= 1) {
    if (tid < off) { s0[tid] += s0[tid + off]; s1[tid] += s1[tid + off]; }
    __syncthreads();
  }
  if (tid == 0) {
    float y0 = s0[0] + b_out[0], y1 = s1[0] + b_out[1];
    float mx = fmaxf(y0, y1);
    float lse = mx + logf(expf(y0 - mx) + expf(y1 - mx));
    out[0] = y0 - lse;
    out[1] = y1 - lse;
  }
}

// ---------------------------------------------------------------------------
extern "C" void kernel_launch(void* const* d_in, const int* in_sizes, int n_in,
                              void* d_out, int out_size, void* d_ws, size_t ws_size,
                              hipStream_t stream) {
  const int*   sent  = (const int*)d_in[0];
  const float* emb   = (const float*)d_in[1];
  const float* w_ih  = (const float*)d_in[2];
  const float* w_hh  = (const float*)d_in[3];
  const float* b_ih  = (const float*)d_in[4];
  const float* b_hh  = (const float*)d_in[5];
  const float* w_out = (const float*)d_in[6];
  const float* b_out = (const float*)d_in[7];
  float* out = (float*)d_out;

  // workspace layout
  unsigned long long* slots = (unsigned long long*)d_ws;       // 2*512*8 = 8 KB
  int* flags = (int*)((char*)d_ws + 8192);                     // 64 ints
  void* xg   = (char*)d_ws + 16384;                            // SEQ*NG bf16

  // only the flags need zeroing (slots self-initialize in the kernel)
  hipMemsetAsync(flags, 0, 256, stream);

  // fused producer+consumer: 128 recurrence WGs + 128 GEMM workers,
  // co-scheduled in ONE launch (same-stream kernels serialize; round-10 lesson)
  fused_lstm<<<NWG + NWORK, RT, 0, stream>>>(
      sent, emb, w_ih, b_ih, b_hh, w_hh,
      (unsigned long long*)xg, slots, flags);

  // head: final h tagged 4096 lives in slots buffer 0
  head_kernel<<<1, 256, 0, stream>>>(slots, w_out, b_out, out);
}